// Round 1
// baseline (1102.300 us; speedup 1.0000x reference)
//
#include <hip/hip_runtime.h>

#define Bn 4
#define Cn 256
#define CQn 64
#define Nn 4096
#define NP 4104   // pLds row stride in halves: 8208 B = 16B-aligned, bank-stride 4
#define SCP 268   // scat row stride in f32: 1072 B = 16B-aligned, ≡12 mod 32 (uniform banks)

using f32x4  = __attribute__((ext_vector_type(4))) float;
using half4  = __attribute__((ext_vector_type(4))) _Float16;
using half8  = __attribute__((ext_vector_type(8))) _Float16;

#define MFMA_F16(a, b, c)  __builtin_amdgcn_mfma_f32_16x16x32_f16((a), (b), (c), 0, 0, 0)

// ---------------------------------------------------------------------------
// P1: q/k1/k2 projections. out_t[b][n][o] = sum_c W[o][c] x[b][c][n] + bias[o]
// stored f16, layout (B, N, 64). blockIdx.z selects proj (0:q<-x3, 1:k1<-x1, 2:k2<-x2).
// x-fragment loads double-buffered across kst (wrap-indexed, in-range).
// ---------------------------------------------------------------------------
__global__ __launch_bounds__(256) void proj_qk(
    const float* __restrict__ x1, const float* __restrict__ x2,
    const float* __restrict__ x3,
    const float* __restrict__ Wq, const float* __restrict__ bq,
    const float* __restrict__ Wk, const float* __restrict__ bk,
    const float* __restrict__ Wk2, const float* __restrict__ bk2,
    _Float16* __restrict__ qt, _Float16* __restrict__ k1t, _Float16* __restrict__ k2t)
{
  const int p = blockIdx.z;
  const float* x    = (p == 0) ? x3 : (p == 1) ? x1 : x2;
  const float* W    = (p == 0) ? Wq : (p == 1) ? Wk : Wk2;
  const float* bias = (p == 0) ? bq : (p == 1) ? bk : bk2;
  _Float16* out     = (p == 0) ? qt : (p == 1) ? k1t : k2t;

  const int b = blockIdx.y;
  const int n0 = blockIdx.x * 64;
  const int tid = threadIdx.x;
  const int w = tid >> 6, lane = tid & 63, quad = lane >> 4, l16 = lane & 15;
  const int n_row = n0 + w * 16 + l16;  // A row
  const float* xb = x + (size_t)b * Cn * Nn;

  f32x4 acc[4] = {};
  half8 a_cur;
  {
    const int c0 = quad * 8;
#pragma unroll
    for (int j = 0; j < 8; ++j) a_cur[j] = (_Float16)xb[(size_t)(c0 + j) * Nn + n_row];
  }
  for (int kst = 0; kst < 8; ++kst) {
    const int c  = kst * 32 + quad * 8;
    const int cn = ((kst + 1) & 7) * 32 + quad * 8;
    half8 a_nxt;
#pragma unroll
    for (int j = 0; j < 8; ++j) a_nxt[j] = (_Float16)xb[(size_t)(cn + j) * Nn + n_row];
#pragma unroll
    for (int s = 0; s < 4; ++s) {
      const int o = s * 16 + l16;
      const f32x4 w0 = *(const f32x4*)(W + (size_t)o * Cn + c);
      const f32x4 w1 = *(const f32x4*)(W + (size_t)o * Cn + c + 4);
      half8 bf;
#pragma unroll
      for (int j = 0; j < 4; ++j) { bf[j] = (_Float16)w0[j]; bf[4 + j] = (_Float16)w1[j]; }
      acc[s] = MFMA_F16(a_cur, bf, acc[s]);
    }
    a_cur = a_nxt;
  }
#pragma unroll
  for (int s = 0; s < 4; ++s) {
    const int o = s * 16 + l16;
    const float bb = bias[o];
#pragma unroll
    for (int r = 0; r < 4; ++r) {
      const int n = n0 + w * 16 + quad * 4 + r;  // D row
      out[((size_t)b * Nn + n) * CQn + o] = (_Float16)(acc[s][r] + bb);
    }
  }
}

// ---------------------------------------------------------------------------
// P2: v/vt projections. out[b][o][n] = sum_c W[o][c] x[b][c][n] + bias[o]
// f16, natural layout (B, C, N). blockIdx.z: 0: v<-x3, 1: vt<-xt.
// x-fragment loads double-buffered across kst (wrap-indexed, in-range).
// ---------------------------------------------------------------------------
__global__ __launch_bounds__(256) void proj_v(
    const float* __restrict__ x3, const float* __restrict__ xt,
    const float* __restrict__ Wv, const float* __restrict__ bv,
    const float* __restrict__ Wv2, const float* __restrict__ bv2,
    _Float16* __restrict__ v, _Float16* __restrict__ vt)
{
  const int p = blockIdx.z;
  const float* x    = p ? xt : x3;
  const float* W    = p ? Wv2 : Wv;
  const float* bias = p ? bv2 : bv;
  _Float16* out     = p ? vt : v;

  const int b = blockIdx.y;
  const int n0 = blockIdx.x * 32;
  const int tid = threadIdx.x;
  const int w = tid >> 6, lane = tid & 63, quad = lane >> 4, l16 = lane & 15;
  const float* xb = x + (size_t)b * Cn * Nn;

  f32x4 acc[4][2] = {};
  half8 bc[2];
  {
    const int c0 = quad * 8;
#pragma unroll
    for (int t = 0; t < 2; ++t) {
      const int n = n0 + t * 16 + l16;
#pragma unroll
      for (int j = 0; j < 8; ++j) bc[t][j] = (_Float16)xb[(size_t)(c0 + j) * Nn + n];
    }
  }
  for (int kst = 0; kst < 8; ++kst) {
    const int c  = kst * 32 + quad * 8;
    const int cn = ((kst + 1) & 7) * 32 + quad * 8;
    half8 bn[2];
#pragma unroll
    for (int t = 0; t < 2; ++t) {
      const int n = n0 + t * 16 + l16;
#pragma unroll
      for (int j = 0; j < 8; ++j) bn[t][j] = (_Float16)xb[(size_t)(cn + j) * Nn + n];
    }
#pragma unroll
    for (int s = 0; s < 4; ++s) {
      const int o = w * 64 + s * 16 + l16;
      const f32x4 w0 = *(const f32x4*)(W + (size_t)o * Cn + c);
      const f32x4 w1 = *(const f32x4*)(W + (size_t)o * Cn + c + 4);
      half8 a;
#pragma unroll
      for (int j = 0; j < 4; ++j) { a[j] = (_Float16)w0[j]; a[4 + j] = (_Float16)w1[j]; }
#pragma unroll
      for (int t = 0; t < 2; ++t) acc[s][t] = MFMA_F16(a, bc[t], acc[s][t]);
    }
    bc[0] = bn[0]; bc[1] = bn[1];
  }
#pragma unroll
  for (int s = 0; s < 4; ++s) {
#pragma unroll
    for (int r = 0; r < 4; ++r) {
      const int o = w * 64 + s * 16 + quad * 4 + r;  // D row
      const float bb = bias[o];
#pragma unroll
      for (int t = 0; t < 2; ++t) {
        const int n = n0 + t * 16 + l16;  // D col
        out[((size_t)b * Cn + o) * Nn + n] = (_Float16)(acc[s][t][r] + bb);
      }
    }
  }
}

// ---------------------------------------------------------------------------
// Fused v3: one 1024-thread block (16 waves, 4/SIMD) per 16 attn rows.
// LDS union: pLds 16 x 4104 f16 (128 KB) overlaid by scat[2][4][16][268] f32
// (134 KB) for the epilogue reduce; + red + rLs = ~136 KB total. 6 barriers.
//  pass1: waves split m 16-way (256 each): l1,l2 partials -> LDS reduce.
//         K-fragments double-buffered; wrap prefetch preloads pass2's mi=0.
//  pass2: recompute S, pp=exp(a1+a2) -> pLds (f16, UNNORMALIZED); L -> rLs.
//  PV:    waves = 4 m-chunks x 4 c-chunks; all 9 fragments double-buffered
//         (prefetch it+1 before MFMAs of it); attn f32 write (pp * 1/L)
//         interleaved one 256-col chunk per even iteration -> store latency
//         drains under MFMA. 1/L folded into epilogue (one fewer f16 round).
//  reduce: scatter acc via ds_write_b128 into scat (conflict-free stride),
//         one barrier, gather 4 wm-partials + write out1,out2 directly.
// ---------------------------------------------------------------------------
union ShU {
  _Float16 pLds[16][NP];            // 131,328 B
  float scat[2][4][16][SCP];        // 137,216 B  [set][wm][n][c]
};

__global__ __launch_bounds__(1024, 4) void attn_fused(
    const _Float16* __restrict__ qt, const _Float16* __restrict__ k1t,
    const _Float16* __restrict__ k2t, const _Float16* __restrict__ v,
    const _Float16* __restrict__ vt,
    const float* __restrict__ x3, const float* __restrict__ xt,
    const float* __restrict__ gamma, const float* __restrict__ gamma2,
    float* __restrict__ attn, float* __restrict__ out1, float* __restrict__ out2)
{
  __shared__ ShU sh;
  __shared__ float red[16][2][16];
  __shared__ __align__(16) float rLs[16];

  const int i = blockIdx.x;
  const int b = (i & 7) >> 1;                      // batch pinned to XCD pair
  const int nt = ((i >> 3) << 1) | (i & 1);        // 0..255
  const int n0 = nt * 16;
  const int tid = threadIdx.x;
  const int w = tid >> 6, lane = tid & 63, quad = lane >> 4, l16 = lane & 15;
  const int m_lo = w * 256;                        // this wave's m-chunk (pass1/2)

  const _Float16* qrow = qt + ((size_t)b * Nn + n0 + l16) * CQn;
  const half8 aq0 = *(const half8*)(qrow + quad * 8);
  const half8 aq1 = *(const half8*)(qrow + 32 + quad * 8);
  const _Float16* k1p = k1t + (size_t)b * Nn * CQn + (size_t)(m_lo + l16) * CQn + quad * 8;
  const _Float16* k2p = k2t + (size_t)b * Nn * CQn + (size_t)(m_lo + l16) * CQn + quad * 8;

  // ---- pass 1: partial row sums of exp(S1), exp(S2) over own 256-m chunk
  float l1a[4] = {0.f, 0.f, 0.f, 0.f}, l2a[4] = {0.f, 0.f, 0.f, 0.f};
  half8 kc0 = *(const half8*)(k1p);
  half8 kc1 = *(const half8*)(k1p + 32);
  half8 kc2 = *(const half8*)(k2p);
  half8 kc3 = *(const half8*)(k2p + 32);
#pragma unroll 2
  for (int mi = 0; mi < 16; ++mi) {
    const int noff = ((mi + 1) & 15) * (16 * CQn);   // wrap: last prefetch = pass2 mi=0
    half8 kn0 = *(const half8*)(k1p + noff);
    half8 kn1 = *(const half8*)(k1p + noff + 32);
    half8 kn2 = *(const half8*)(k2p + noff);
    half8 kn3 = *(const half8*)(k2p + noff + 32);
    f32x4 S1 = {};
    S1 = MFMA_F16(aq0, kc0, S1);
    S1 = MFMA_F16(aq1, kc1, S1);
    f32x4 S2 = {};
    S2 = MFMA_F16(aq0, kc2, S2);
    S2 = MFMA_F16(aq1, kc3, S2);
#pragma unroll
    for (int r = 0; r < 4; ++r) { l1a[r] += __expf(S1[r]); l2a[r] += __expf(S2[r]); }
    kc0 = kn0; kc1 = kn1; kc2 = kn2; kc3 = kn3;
  }
#pragma unroll
  for (int r = 0; r < 4; ++r) {
#pragma unroll
    for (int off = 1; off < 16; off <<= 1) {
      l1a[r] += __shfl_xor(l1a[r], off);
      l2a[r] += __shfl_xor(l2a[r], off);
    }
  }
  if (l16 == 0) {
#pragma unroll
    for (int r = 0; r < 4; ++r) { red[w][0][quad * 4 + r] = l1a[r]; red[w][1][quad * 4 + r] = l2a[r]; }
  }
  __syncthreads();
  float lg1[4], lg2[4];
#pragma unroll
  for (int r = 0; r < 4; ++r) {
    const int n = quad * 4 + r;
    float s1 = 0.f, s2 = 0.f;
#pragma unroll
    for (int ww = 0; ww < 16; ++ww) { s1 += red[ww][0][n]; s2 += red[ww][1][n]; }
    lg1[r] = __logf(s1); lg2[r] = __logf(s2);
  }
  __syncthreads();   // red reused for L below

  // ---- pass 2: pp = exp(exp(S1-lg1)+exp(S2-lg2)) -> pLds (f16, unnormalized)
  // kc0..3 already hold mi=0 fragments (pass1's wrap prefetch).
  float La[4] = {0.f, 0.f, 0.f, 0.f};
#pragma unroll 2
  for (int mi = 0; mi < 16; ++mi) {
    const int m0 = m_lo + mi * 16;
    const int noff = ((mi + 1) & 15) * (16 * CQn);
    half8 kn0 = *(const half8*)(k1p + noff);
    half8 kn1 = *(const half8*)(k1p + noff + 32);
    half8 kn2 = *(const half8*)(k2p + noff);
    half8 kn3 = *(const half8*)(k2p + noff + 32);
    f32x4 S1 = {};
    S1 = MFMA_F16(aq0, kc0, S1);
    S1 = MFMA_F16(aq1, kc1, S1);
    f32x4 S2 = {};
    S2 = MFMA_F16(aq0, kc2, S2);
    S2 = MFMA_F16(aq1, kc3, S2);
#pragma unroll
    for (int r = 0; r < 4; ++r) {
      const float a1 = __expf(S1[r] - lg1[r]);
      const float a2 = __expf(S2[r] - lg2[r]);
      const float pp = __expf(a1 + a2);
      La[r] += pp;
      sh.pLds[quad * 4 + r][m0 + l16] = (_Float16)pp;
    }
    kc0 = kn0; kc1 = kn1; kc2 = kn2; kc3 = kn3;
  }
#pragma unroll
  for (int r = 0; r < 4; ++r) {
#pragma unroll
    for (int off = 1; off < 16; off <<= 1) La[r] += __shfl_xor(La[r], off);
  }
  if (l16 == 0) {
#pragma unroll
    for (int r = 0; r < 4; ++r) red[w][0][quad * 4 + r] = La[r];
  }
  __syncthreads();
  if (tid < 16) {
    float s = 0.f;
#pragma unroll
    for (int ww = 0; ww < 16; ++ww) s += red[ww][0][tid];
    rLs[tid] = 1.0f / s;
  }
  __syncthreads();

  // ---- PV: wave (wm, wc): m in [1024*wm, +1024), c in [64*wc, +64)
  // Double-buffered fragments; attn write interleaved on even iterations.
  const int wm = w & 3, wc = w >> 2;
  const int cb = wc * 64;
  const _Float16* a1p = v  + (size_t)b * Cn * Nn + (size_t)(cb + l16) * Nn + wm * 1024 + quad * 8;
  const _Float16* a2p = vt + (size_t)b * Cn * Nn + (size_t)(cb + l16) * Nn + wm * 1024 + quad * 8;
  const _Float16* bp  = &sh.pLds[l16][wm * 1024 + quad * 8];
  const float rlw = rLs[w];
  float* const arow = attn + ((size_t)b * Nn + n0 + w) * Nn;

  f32x4 acc1[4] = {}, acc2[4] = {};
  half8 Bc = *(const half8*)bp;
  half8 A1c[4], A2c[4];
#pragma unroll
  for (int s = 0; s < 4; ++s) {
    A1c[s] = *(const half8*)(a1p + (size_t)s * 16 * Nn);
    A2c[s] = *(const half8*)(a2p + (size_t)s * 16 * Nn);
  }
#pragma unroll 2
  for (int it = 0; it < 32; ++it) {
    const int noff = ((it + 1) & 31) * 32;           // wrap keeps prefetch in-range
    half8 Bn_ = *(const half8*)(bp + noff);
    half8 A1n[4], A2n[4];
#pragma unroll
    for (int s = 0; s < 4; ++s) {
      A1n[s] = *(const half8*)(a1p + (size_t)s * 16 * Nn + noff);
      A2n[s] = *(const half8*)(a2p + (size_t)s * 16 * Nn + noff);
    }
    if ((it & 1) == 0) {                             // attn write: row w, 256-col chunk
      const int col = (it >> 1) * 256 + lane * 4;
      const half4 h = *(const half4*)(&sh.pLds[w][col]);
      f32x4 o;
#pragma unroll
      for (int j = 0; j < 4; ++j) o[j] = (float)h[j] * rlw;
      *(f32x4*)(arow + col) = o;
    }
#pragma unroll
    for (int s = 0; s < 4; ++s) acc1[s] = MFMA_F16(A1c[s], Bc, acc1[s]);
#pragma unroll
    for (int s = 0; s < 4; ++s) acc2[s] = MFMA_F16(A2c[s], Bc, acc2[s]);
    Bc = Bn_;
#pragma unroll
    for (int s = 0; s < 4; ++s) { A1c[s] = A1n[s]; A2c[s] = A2n[s]; }
  }

  // ---- scatter partials into LDS (pLds reuse), single barrier, gather+epilogue
  __syncthreads();   // all pLds reads done; union flips to scat
#pragma unroll
  for (int s = 0; s < 4; ++s) {
    *(f32x4*)&sh.scat[0][wm][l16][cb + s * 16 + quad * 4] = acc1[s];
    *(f32x4*)&sh.scat[1][wm][l16][cb + s * 16 + quad * 4] = acc2[s];
  }
  __syncthreads();
  {
    const int c = tid >> 2, nq = (tid & 3) * 4;
    const float g1 = gamma[0], g2 = gamma2[0];
    f32x4 s1 = {}, s2 = {};
#pragma unroll
    for (int r = 0; r < 4; ++r) {
#pragma unroll
      for (int j = 0; j < 4; ++j) {
        s1[j] += sh.scat[0][r][nq + j][c];
        s2[j] += sh.scat[1][r][nq + j][c];
      }
    }
    const size_t base = ((size_t)b * Cn + c) * Nn + n0 + nq;
    f32x4 o1, o2;
#pragma unroll
    for (int j = 0; j < 4; ++j) {
      const float rl = rLs[nq + j];
      o1[j] = g1 * s1[j] * rl + x3[base + j];
      o2[j] = g2 * s2[j] * rl + xt[base + j];
    }
    *(f32x4*)(out1 + base) = o1;
    *(f32x4*)(out2 + base) = o2;
  }
}

// ---------------------------------------------------------------------------
extern "C" void kernel_launch(void* const* d_in, const int* in_sizes, int n_in,
                              void* d_out, int out_size, void* d_ws, size_t ws_size,
                              hipStream_t stream) {
  const float* x1  = (const float*)d_in[0];
  const float* x2  = (const float*)d_in[1];
  const float* x3  = (const float*)d_in[2];
  const float* xt  = (const float*)d_in[3];
  const float* Wq  = (const float*)d_in[4];
  const float* bq  = (const float*)d_in[5];
  const float* Wk  = (const float*)d_in[6];
  const float* bk  = (const float*)d_in[7];
  const float* Wk2 = (const float*)d_in[8];
  const float* bk2 = (const float*)d_in[9];
  const float* Wv  = (const float*)d_in[10];
  const float* bv  = (const float*)d_in[11];
  const float* Wv2 = (const float*)d_in[12];
  const float* bv2 = (const float*)d_in[13];
  const float* gamma  = (const float*)d_in[14];
  const float* gamma2 = (const float*)d_in[15];

  float* outp = (float*)d_out;
  float* attn = outp;                                   // B*N*N
  float* out1 = outp + (size_t)Bn * Nn * Nn;            // B*C*N
  float* out2 = out1 + (size_t)Bn * Cn * Nn;

  _Float16* qt  = (_Float16*)d_ws;                      // B*N*CQ f16
  _Float16* k1t = qt + (size_t)Bn * Nn * CQn;
  _Float16* k2t = k1t + (size_t)Bn * Nn * CQn;
  _Float16* v   = k2t + (size_t)Bn * Nn * CQn;          // B*C*N f16
  _Float16* vt  = v + (size_t)Bn * Cn * Nn;

  proj_qk<<<dim3(Nn / 64, Bn, 3), 256, 0, stream>>>(x1, x2, x3, Wq, bq, Wk, bk, Wk2, bk2,
                                                    qt, k1t, k2t);
  proj_v<<<dim3(Nn / 32, Bn, 2), 256, 0, stream>>>(x3, xt, Wv, bv, Wv2, bv2, v, vt);
  attn_fused<<<dim3(Bn * Nn / 16), 1024, 0, stream>>>(qt, k1t, k2t, v, vt, x3, xt,
                                                      gamma, gamma2, attn, out1, out2);
}

// Round 2
// 607.511 us; speedup vs baseline: 1.8145x; 1.8145x over previous
//
#include <hip/hip_runtime.h>

#define Bn 4
#define Cn 256
#define CQn 64
#define Nn 4096

using f32x4  = __attribute__((ext_vector_type(4))) float;
using half4  = __attribute__((ext_vector_type(4))) _Float16;
using half8  = __attribute__((ext_vector_type(8))) _Float16;

#define MFMA_F16(a, b, c)  __builtin_amdgcn_mfma_f32_16x16x32_f16((a), (b), (c), 0, 0, 0)
// XOR swizzle on byte-in-row: flips bits 4..6 by (row&7). Same involution on both
// write and read sides (rule: both-sides-or-neither). Makes 16-lane row-strided
// ds_read_b128 2-way (free) instead of 16-way conflicted.
#define SWZ(row, byte) ((unsigned)(byte) ^ ((((unsigned)(row)) & 7u) << 4))

// LDS tiles with 128-byte rows (64 f16), swizzled.
__device__ __forceinline__ half8 lds_read8(const _Float16* base, int row, int slot) {
  return *(const half8*)((const char*)base + row * 128 + SWZ(row, slot * 16));
}
__device__ __forceinline__ void lds_write8(_Float16* base, int row, int slot, half8 v) {
  *(half8*)((char*)base + row * 128 + SWZ(row, slot * 16)) = v;
}

// ---------------------------------------------------------------------------
// proj_all: all 5 projections. z = 0:q<-x3, 1:k1<-x1, 2:k2<-x2, 3:v<-x3, 4:vt<-xt.
// Block: 256 threads, 64 n-columns. x-tile (256c x 64n) LDS-transposed to
// xT[n][c] (f16, 512B rows, swizzled) via coalesced f32x4 loads + in-thread
// 4x4 transpose. Kills the stride-16KB scalar x loads of the old proj kernels.
// ---------------------------------------------------------------------------
__global__ __launch_bounds__(256) void proj_all(
    const float* __restrict__ x1, const float* __restrict__ x2,
    const float* __restrict__ x3, const float* __restrict__ xt,
    const float* __restrict__ Wq, const float* __restrict__ bq,
    const float* __restrict__ Wk, const float* __restrict__ bk,
    const float* __restrict__ Wk2, const float* __restrict__ bk2,
    const float* __restrict__ Wv, const float* __restrict__ bv,
    const float* __restrict__ Wv2, const float* __restrict__ bv2,
    _Float16* __restrict__ qt, _Float16* __restrict__ k1t, _Float16* __restrict__ k2t,
    _Float16* __restrict__ v, _Float16* __restrict__ vt)
{
  const int p = blockIdx.z;
  const float* x    = (p == 0 || p == 3) ? x3 : (p == 1) ? x1 : (p == 2) ? x2 : xt;
  const float* W    = (p == 0) ? Wq : (p == 1) ? Wk : (p == 2) ? Wk2 : (p == 3) ? Wv : Wv2;
  const float* bias = (p == 0) ? bq : (p == 1) ? bk : (p == 2) ? bk2 : (p == 3) ? bv : bv2;

  const int b = blockIdx.y;
  const int n0 = blockIdx.x * 64;
  const int tid = threadIdx.x;
  const int w = tid >> 6, lane = tid & 63, quad = lane >> 4, l16 = lane & 15;

  __shared__ _Float16 xT[64 * 256];   // [n][c], 512 B rows, swizzled. 32 KB.

  // ---- stage + transpose: 4 iters x (4 coalesced f32x4 loads -> 4 half4 writes)
  {
    const int nq = (tid & 15) * 4;
#pragma unroll
    for (int it = 0; it < 4; ++it) {
      const int cg = it * 64 + (tid >> 4) * 4;
      f32x4 xv[4];
#pragma unroll
      for (int ci = 0; ci < 4; ++ci)
        xv[ci] = *(const f32x4*)(x + ((size_t)b * Cn + cg + ci) * Nn + n0 + nq);
#pragma unroll
      for (int ni = 0; ni < 4; ++ni) {
        const int row = nq + ni;
        half4 hv;
#pragma unroll
        for (int ci = 0; ci < 4; ++ci) hv[ci] = (_Float16)xv[ci][ni];
        *(half4*)((char*)xT + row * 512 + SWZ(row, cg * 2)) = hv;
      }
    }
  }
  __syncthreads();

  if (p < 3) {
    // wave w: n-rows w*16..+16 (A), all 64 o (B=W). out[b][n][o] f16.
    _Float16* out = (p == 0) ? qt : (p == 1) ? k1t : k2t;
    const int row = w * 16 + l16;
    f32x4 acc[4] = {};
    for (int kst = 0; kst < 8; ++kst) {
      const half8 a = *(const half8*)((const char*)xT + row * 512 +
                                      SWZ(row, (kst * 4 + quad) * 16));
#pragma unroll
      for (int s = 0; s < 4; ++s) {
        const int o = s * 16 + l16;
        const f32x4 w0 = *(const f32x4*)(W + (size_t)o * Cn + kst * 32 + quad * 8);
        const f32x4 w1 = *(const f32x4*)(W + (size_t)o * Cn + kst * 32 + quad * 8 + 4);
        half8 bf;
#pragma unroll
        for (int j = 0; j < 4; ++j) { bf[j] = (_Float16)w0[j]; bf[4 + j] = (_Float16)w1[j]; }
        acc[s] = MFMA_F16(a, bf, acc[s]);
      }
    }
#pragma unroll
    for (int s = 0; s < 4; ++s) {
      const int o = s * 16 + l16;
      const float bb = bias[o];
#pragma unroll
      for (int r = 0; r < 4; ++r) {
        const int n = n0 + w * 16 + quad * 4 + r;
        out[((size_t)b * Nn + n) * CQn + o] = (_Float16)(acc[s][r] + bb);
      }
    }
  } else {
    // wave w: o-rows w*64..+64 (A=W), all 64 n (B=xT). out[b][o][n] f16.
    _Float16* out = (p == 3) ? v : vt;
    f32x4 acc[4][4] = {};   // [s: o-tile][tt: n-tile]
    for (int kst = 0; kst < 8; ++kst) {
      half8 bt[4];
#pragma unroll
      for (int tt = 0; tt < 4; ++tt) {
        const int rowx = tt * 16 + l16;
        bt[tt] = *(const half8*)((const char*)xT + rowx * 512 +
                                 SWZ(rowx, (kst * 4 + quad) * 16));
      }
#pragma unroll
      for (int s = 0; s < 4; ++s) {
        const int o = w * 64 + s * 16 + l16;
        const f32x4 w0 = *(const f32x4*)(W + (size_t)o * Cn + kst * 32 + quad * 8);
        const f32x4 w1 = *(const f32x4*)(W + (size_t)o * Cn + kst * 32 + quad * 8 + 4);
        half8 a;
#pragma unroll
        for (int j = 0; j < 4; ++j) { a[j] = (_Float16)w0[j]; a[4 + j] = (_Float16)w1[j]; }
#pragma unroll
        for (int tt = 0; tt < 4; ++tt) acc[s][tt] = MFMA_F16(a, bt[tt], acc[s][tt]);
      }
    }
#pragma unroll
    for (int s = 0; s < 4; ++s) {
#pragma unroll
      for (int r = 0; r < 4; ++r) {
        const int o = w * 64 + s * 16 + quad * 4 + r;
        const float bb = bias[o];
#pragma unroll
        for (int tt = 0; tt < 4; ++tt) {
          const int n = n0 + tt * 16 + l16;
          out[((size_t)b * Cn + o) * Nn + n] = (_Float16)(acc[s][tt][r] + bb);
        }
      }
    }
  }
}

// ---------------------------------------------------------------------------
// attn_flash: 256 blocks (1/CU), 1024 threads (16 waves), 64 attn rows/block.
// 4x fewer v/vt re-reads than the 16-row version; all global reads coalesced
// and staged through swizzled LDS. Three m-sweeps over 64-wide tiles:
//   sweep1: lg1/lg2 = log sum exp(S1/S2)        (K staged, dbuf)
//   sweep2: L = sum exp(exp(S1-lg1)+exp(S2-lg2)) -> rLs
//   sweep3: pp tile -> LDS; PV MFMA accumulate; attn = pp*rL written per tile.
// S waves: (n-tile w&3, m-sub w>>2). PV waves: c-rows w*16..+16 (no x-wave reduce).
// LDS ~117 KB. Reg-staged global->LDS (load at phase top, ds_write at bottom).
// ---------------------------------------------------------------------------
__global__ __launch_bounds__(1024, 4) void attn_flash(
    const _Float16* __restrict__ qt, const _Float16* __restrict__ k1t,
    const _Float16* __restrict__ k2t, const _Float16* __restrict__ v,
    const _Float16* __restrict__ vt,
    const float* __restrict__ x3, const float* __restrict__ xt,
    const float* __restrict__ gamma, const float* __restrict__ gamma2,
    float* __restrict__ attn, float* __restrict__ out1, float* __restrict__ out2)
{
  __shared__ _Float16 qT[64 * 64];          //  8 KB
  __shared__ _Float16 Kt[2][2][64 * 64];    // 32 KB [buf][tensor]
  __shared__ _Float16 Vt[2][256 * 64];      // 64 KB [tensor]
  __shared__ _Float16 ppT[64 * 64];         //  8 KB
  __shared__ float red[16][2][16];
  __shared__ float rLs[64];

  const int i = blockIdx.x;
  const int b = (i & 7) >> 1;                   // batch pinned to XCD pair
  const int nt = ((i >> 3) << 1) | (i & 1);     // 0..63
  const int n0 = nt * 64;
  const int tid = threadIdx.x;
  const int w = tid >> 6, lane = tid & 63, quad = lane >> 4, l16 = lane & 15;
  const int ntw = w & 3;     // n-tile (S phases)
  const int ms  = w >> 2;    // m-sub  (S phases)

  const _Float16* k1b = k1t + (size_t)b * Nn * CQn;
  const _Float16* k2b = k2t + (size_t)b * Nn * CQn;
  const _Float16* vb  = v   + (size_t)b * Cn * Nn;
  const _Float16* vtb = vt  + (size_t)b * Cn * Nn;
  const float g1 = gamma[0], g2 = gamma2[0];

  // ---- stage qT (64 x 64 f16): thread covers 8 B
  {
    const int row = tid >> 4, s8 = tid & 15;
    const half4 qv = *(const half4*)(qt + ((size_t)b * Nn + n0 + row) * CQn + s8 * 4);
    *(half4*)((char*)qT + row * 128 + SWZ(row, s8 * 8)) = qv;
  }

  // ---- per-thread K staging geometry (16 KB tile: thread covers 16 B)
  const int k_te  = tid >> 9;
  const int k_row = (tid >> 3) & 63;
  const int k_sl  = tid & 7;
  const _Float16* kSrcBase = (k_te ? k2b : k1b) + (size_t)k_row * CQn + k_sl * 8;
  _Float16* kDst0 = (_Float16*)((char*)Kt[0][k_te] + k_row * 128 + SWZ(k_row, k_sl * 16));
  _Float16* kDst1 = (_Float16*)((char*)Kt[1][k_te] + k_row * 128 + SWZ(k_row, k_sl * 16));
  // stage K tile 0 into buf 0
  *(half8*)kDst0 = *(const half8*)kSrcBase;
  __syncthreads();

  const half8 aq0 = lds_read8(qT, ntw * 16 + l16, quad);
  const half8 aq1 = lds_read8(qT, ntw * 16 + l16, 4 + quad);
  const int krow = ms * 16 + l16;

  // ================= sweep 1: lg1/lg2 =================
  float l1a[4] = {0.f, 0.f, 0.f, 0.f}, l2a[4] = {0.f, 0.f, 0.f, 0.f};
#pragma unroll 1
  for (int t = 0; t < 64; ++t) {
    const int mn = ((t + 1) & 63) * 64;
    const half8 kreg = *(const half8*)(kSrcBase + (size_t)mn * CQn);
    const _Float16* Kc0 = Kt[t & 1][0];
    const _Float16* Kc1 = Kt[t & 1][1];
    const half8 kb0 = lds_read8(Kc0, krow, quad);
    const half8 kb1 = lds_read8(Kc0, krow, 4 + quad);
    const half8 kb2 = lds_read8(Kc1, krow, quad);
    const half8 kb3 = lds_read8(Kc1, krow, 4 + quad);
    f32x4 S1 = {}; S1 = MFMA_F16(aq0, kb0, S1); S1 = MFMA_F16(aq1, kb1, S1);
    f32x4 S2 = {}; S2 = MFMA_F16(aq0, kb2, S2); S2 = MFMA_F16(aq1, kb3, S2);
#pragma unroll
    for (int r = 0; r < 4; ++r) { l1a[r] += __expf(S1[r]); l2a[r] += __expf(S2[r]); }
    *(half8*)(((t + 1) & 1) ? kDst1 : kDst0) = kreg;
    __syncthreads();
  }
#pragma unroll
  for (int r = 0; r < 4; ++r)
#pragma unroll
    for (int off = 1; off < 16; off <<= 1) {
      l1a[r] += __shfl_xor(l1a[r], off);
      l2a[r] += __shfl_xor(l2a[r], off);
    }
  if (l16 == 0)
#pragma unroll
    for (int r = 0; r < 4; ++r) { red[w][0][quad * 4 + r] = l1a[r]; red[w][1][quad * 4 + r] = l2a[r]; }
  __syncthreads();
  float lg1[4], lg2[4];
#pragma unroll
  for (int r = 0; r < 4; ++r) {
    const int nn = quad * 4 + r;
    float s1 = 0.f, s2 = 0.f;
#pragma unroll
    for (int msk = 0; msk < 4; ++msk) { s1 += red[ntw + 4 * msk][0][nn]; s2 += red[ntw + 4 * msk][1][nn]; }
    lg1[r] = __logf(s1); lg2[r] = __logf(s2);
  }
  __syncthreads();

  // ================= sweep 2: L -> rLs =================
  float La[4] = {0.f, 0.f, 0.f, 0.f};
#pragma unroll 1
  for (int t = 0; t < 64; ++t) {
    const int mn = ((t + 1) & 63) * 64;
    const half8 kreg = *(const half8*)(kSrcBase + (size_t)mn * CQn);
    const _Float16* Kc0 = Kt[t & 1][0];
    const _Float16* Kc1 = Kt[t & 1][1];
    const half8 kb0 = lds_read8(Kc0, krow, quad);
    const half8 kb1 = lds_read8(Kc0, krow, 4 + quad);
    const half8 kb2 = lds_read8(Kc1, krow, quad);
    const half8 kb3 = lds_read8(Kc1, krow, 4 + quad);
    f32x4 S1 = {}; S1 = MFMA_F16(aq0, kb0, S1); S1 = MFMA_F16(aq1, kb1, S1);
    f32x4 S2 = {}; S2 = MFMA_F16(aq0, kb2, S2); S2 = MFMA_F16(aq1, kb3, S2);
#pragma unroll
    for (int r = 0; r < 4; ++r) {
      const float a1 = __expf(S1[r] - lg1[r]);
      const float a2 = __expf(S2[r] - lg2[r]);
      La[r] += __expf(a1 + a2);
    }
    *(half8*)(((t + 1) & 1) ? kDst1 : kDst0) = kreg;
    __syncthreads();
  }
#pragma unroll
  for (int r = 0; r < 4; ++r)
#pragma unroll
    for (int off = 1; off < 16; off <<= 1) La[r] += __shfl_xor(La[r], off);
  if (l16 == 0)
#pragma unroll
    for (int r = 0; r < 4; ++r) red[w][0][quad * 4 + r] = La[r];
  __syncthreads();
  if (tid < 64) {
    float s = 0.f;
#pragma unroll
    for (int msk = 0; msk < 4; ++msk) s += red[(tid >> 4) + 4 * msk][0][tid & 15];
    rLs[tid] = 1.0f / s;
  }
  __syncthreads();

  // ---- per-thread V staging geometry (64 KB tile: thread covers 4 x 16 B)
  const int v_te = tid >> 9;
  const int v_c  = (tid >> 1) & 255;
  const int v_s0 = (tid & 1) * 4;
  const _Float16* vSrcBase = (v_te ? vtb : vb) + (size_t)v_c * Nn + v_s0 * 8;
  char* vDstB = (char*)Vt[v_te] + v_c * 128;

  // ================= sweep 3: pp + PV + attn =================
  f32x4 acc[4][2] = {};   // [n-tile][tensor]
#pragma unroll 1
  for (int t = 0; t < 64; ++t) {
    const int m0 = t * 64;
    const int mn = ((t + 1) & 63) * 64;
    // issue staging loads early (committed to LDS at end of phase A)
    half8 vreg[4];
#pragma unroll
    for (int j = 0; j < 4; ++j) vreg[j] = *(const half8*)(vSrcBase + m0 + j * 8);
    const half8 kreg = *(const half8*)(kSrcBase + (size_t)mn * CQn);
    // S compute from K[t]
    const _Float16* Kc0 = Kt[t & 1][0];
    const _Float16* Kc1 = Kt[t & 1][1];
    const half8 kb0 = lds_read8(Kc0, krow, quad);
    const half8 kb1 = lds_read8(Kc0, krow, 4 + quad);
    const half8 kb2 = lds_read8(Kc1, krow, quad);
    const half8 kb3 = lds_read8(Kc1, krow, 4 + quad);
    f32x4 S1 = {}; S1 = MFMA_F16(aq0, kb0, S1); S1 = MFMA_F16(aq1, kb1, S1);
    f32x4 S2 = {}; S2 = MFMA_F16(aq0, kb2, S2); S2 = MFMA_F16(aq1, kb3, S2);
    // pp (unnormalized, f16) -> ppT
#pragma unroll
    for (int r = 0; r < 4; ++r) {
      const float a1 = __expf(S1[r] - lg1[r]);
      const float a2 = __expf(S2[r] - lg2[r]);
      const float ppv = __expf(a1 + a2);
      const int prow = ntw * 16 + quad * 4 + r;
      const int pcol = ms * 16 + l16;
      *(_Float16*)((char*)ppT + prow * 128 + SWZ(prow, pcol * 2)) = (_Float16)ppv;
    }
    // commit staged tiles
#pragma unroll
    for (int j = 0; j < 4; ++j)
      *(half8*)(vDstB + SWZ(v_c, (v_s0 + j) * 16)) = vreg[j];
    *(half8*)(((t + 1) & 1) ? kDst1 : kDst0) = kreg;
    __syncthreads();                              // barrier1: pp, V[t], K[t+1] ready
    // PV: wave w owns c-rows w*16..+16, all 4 n-tiles
#pragma unroll
    for (int kk = 0; kk < 2; ++kk) {
      const half8 A1 = lds_read8(Vt[0], w * 16 + l16, kk * 4 + quad);
      const half8 A2 = lds_read8(Vt[1], w * 16 + l16, kk * 4 + quad);
#pragma unroll
      for (int nn = 0; nn < 4; ++nn) {
        const half8 pb = lds_read8(ppT, nn * 16 + l16, kk * 4 + quad);
        acc[nn][0] = MFMA_F16(A1, pb, acc[nn][0]);
        acc[nn][1] = MFMA_F16(A2, pb, acc[nn][1]);
      }
    }
    // attn write: thread covers one f32x4 of the 64x64 tile
    {
      const int row = tid >> 4, c4 = (tid & 15) * 4;
      const half4 h = *(const half4*)((const char*)ppT + row * 128 + SWZ(row, c4 * 2));
      const float rl = rLs[row];
      f32x4 o;
#pragma unroll
      for (int jj = 0; jj < 4; ++jj) o[jj] = (float)h[jj] * rl;
      *(f32x4*)(attn + ((size_t)b * Nn + n0 + row) * Nn + m0 + c4) = o;
    }
    __syncthreads();                              // barrier2: tile consumed
  }

  // ---- epilogue: each wave owns distinct c-rows; no cross-wave reduce
#pragma unroll
  for (int nn = 0; nn < 4; ++nn) {
    const float rl = rLs[nn * 16 + l16];
#pragma unroll
    for (int r = 0; r < 4; ++r) {
      const int c = w * 16 + quad * 4 + r;
      const size_t base = ((size_t)b * Cn + c) * Nn + n0 + nn * 16 + l16;
      out1[base] = g1 * acc[nn][0][r] * rl + x3[base];
      out2[base] = g2 * acc[nn][1][r] * rl + xt[base];
    }
  }
}

// ---------------------------------------------------------------------------
extern "C" void kernel_launch(void* const* d_in, const int* in_sizes, int n_in,
                              void* d_out, int out_size, void* d_ws, size_t ws_size,
                              hipStream_t stream) {
  const float* x1  = (const float*)d_in[0];
  const float* x2  = (const float*)d_in[1];
  const float* x3  = (const float*)d_in[2];
  const float* xt  = (const float*)d_in[3];
  const float* Wq  = (const float*)d_in[4];
  const float* bq  = (const float*)d_in[5];
  const float* Wk  = (const float*)d_in[6];
  const float* bk  = (const float*)d_in[7];
  const float* Wk2 = (const float*)d_in[8];
  const float* bk2 = (const float*)d_in[9];
  const float* Wv  = (const float*)d_in[10];
  const float* bv  = (const float*)d_in[11];
  const float* Wv2 = (const float*)d_in[12];
  const float* bv2 = (const float*)d_in[13];
  const float* gamma  = (const float*)d_in[14];
  const float* gamma2 = (const float*)d_in[15];

  float* outp = (float*)d_out;
  float* attn = outp;                                   // B*N*N
  float* out1 = outp + (size_t)Bn * Nn * Nn;            // B*C*N
  float* out2 = out1 + (size_t)Bn * Cn * Nn;

  _Float16* qt  = (_Float16*)d_ws;                      // B*N*CQ f16
  _Float16* k1t = qt + (size_t)Bn * Nn * CQn;
  _Float16* k2t = k1t + (size_t)Bn * Nn * CQn;
  _Float16* v   = k2t + (size_t)Bn * Nn * CQn;          // B*C*N f16
  _Float16* vt  = v + (size_t)Bn * Cn * Nn;

  proj_all<<<dim3(Nn / 64, Bn, 5), 256, 0, stream>>>(
      x1, x2, x3, xt, Wq, bq, Wk, bk, Wk2, bk2, Wv, bv, Wv2, bv2,
      qt, k1t, k2t, v, vt);
  attn_flash<<<dim3(Bn * Nn / 64), 1024, 0, stream>>>(
      qt, k1t, k2t, v, vt, x3, xt, gamma, gamma2, attn, out1, out2);
}